// Round 1
// baseline (862.671 us; speedup 1.0000x reference)
//
#include <hip/hip_runtime.h>
#include <hip/hip_bf16.h>
#include <stdint.h>

// Problem constants
#define NTOK 145
#define MTOK 144
#define CDIM 512
#define NHEAD 8
#define HD 64
#define NWIN 4
#define BWIN 512
#define MROWS (BWIN*NTOK)   // 74240 = 580*128

typedef short short8 __attribute__((ext_vector_type(8)));
typedef float f32x4 __attribute__((ext_vector_type(4)));

__device__ __forceinline__ uint16_t f2bf(float f) {
  union { float f; uint32_t u; } x; x.f = f;
  uint32_t r = x.u + 0x7FFFu + ((x.u >> 16) & 1u);
  return (uint16_t)(r >> 16);
}
__device__ __forceinline__ float bf2f(uint16_t u) {
  union { uint32_t u; float f; } x; x.u = ((uint32_t)u) << 16; return x.f;
}
__device__ __forceinline__ uint32_t pack2(float a, float b) {
  return (uint32_t)f2bf(a) | ((uint32_t)f2bf(b) << 16);
}

// ---------------- prep: weight casts + bias table ----------------
__global__ void prep_kernel(const float* __restrict__ rpb,
                            const float* __restrict__ Wq, const float* __restrict__ bq,
                            const float* __restrict__ Wk, const float* __restrict__ bk,
                            const float* __restrict__ Wv, const float* __restrict__ bv,
                            const float* __restrict__ Wo,
                            uint16_t* __restrict__ wqkv, uint16_t* __restrict__ wo,
                            float* __restrict__ bqkv, float* __restrict__ biastab) {
  int id = blockIdx.x * 256 + threadIdx.x;
  const int A = 1536*512, B = 512*512, C2 = 1536, D = 8*144*144;
  if (id < A) {
    int n = id >> 9, k = id & 511;
    const float* W = (n < 512) ? Wq : (n < 1024) ? Wk : Wv;
    wqkv[id] = f2bf(W[(size_t)(n & 511)*512 + k]);
  } else if ((id -= A) < B) {
    wo[id] = f2bf(Wo[id]);
  } else if ((id -= B) < C2) {
    bqkv[id] = (id < 512) ? bq[id] : (id < 1024) ? bk[id-512] : bv[id-1024];
  } else if ((id -= C2) < D) {
    int h = id / (144*144); int rr = id % (144*144);
    int i = rr / 144, j = rr % 144;
    int rel = (i/12 - j/12 + 11) * 23 + (i%12 - j%12 + 11);
    biastab[id] = rpb[rel*8 + h];
  }
}

// ---------------- GEMM 1: qkv projection ----------------
// out[m,n] = sum_k x[m,k]*wqkv[n,k] + bqkv[n], scattered to q/k/v [B_,H,N,64] bf16
__global__ __launch_bounds__(256) void gemm_qkv(
    const float* __restrict__ x, const uint16_t* __restrict__ wqkv,
    const float* __restrict__ bqkv,
    uint16_t* __restrict__ qb, uint16_t* __restrict__ kb, uint16_t* __restrict__ vb) {
  __shared__ __align__(16) uint16_t As[128*32];
  __shared__ __align__(16) uint16_t Bs[128*32];
  int bid = blockIdx.x;
  int mb = bid / 12, nb = bid % 12;
  int tid = threadIdx.x;
  int lane = tid & 63, w = tid >> 6;
  int wm = w >> 1, wn = w & 1;
  int lm = lane & 15, lq = lane >> 4;
  int sr = tid >> 1, sh = tid & 1;

  const float* agp = x + (size_t)(mb*128 + sr)*512 + sh*16;
  const uint16_t* bgp = wqkv + (size_t)(nb*128 + sr)*512 + sh*16;

  f32x4 acc[4][4];
#pragma unroll
  for (int a = 0; a < 4; a++)
#pragma unroll
    for (int b = 0; b < 4; b++) acc[a][b] = (f32x4){0.f,0.f,0.f,0.f};

  float4 af0 = *(const float4*)(agp+0), af1 = *(const float4*)(agp+4);
  float4 af2 = *(const float4*)(agp+8), af3 = *(const float4*)(agp+12);
  uint4 bu0 = *(const uint4*)(bgp), bu1 = *(const uint4*)(bgp+8);

  for (int kt = 0; kt < 16; kt++) {
    uint32_t p0 = pack2(af0.x, af0.y), p1 = pack2(af0.z, af0.w);
    uint32_t p2 = pack2(af1.x, af1.y), p3 = pack2(af1.z, af1.w);
    uint32_t p4 = pack2(af2.x, af2.y), p5 = pack2(af2.z, af2.w);
    uint32_t p6 = pack2(af3.x, af3.y), p7 = pack2(af3.z, af3.w);
    *(uint4*)&As[sr*32 + sh*16]     = make_uint4(p0,p1,p2,p3);
    *(uint4*)&As[sr*32 + sh*16 + 8] = make_uint4(p4,p5,p6,p7);
    *(uint4*)&Bs[sr*32 + sh*16]     = bu0;
    *(uint4*)&Bs[sr*32 + sh*16 + 8] = bu1;
    __syncthreads();
    if (kt < 15) {
      const float* ag = agp + (kt+1)*32;
      af0 = *(const float4*)(ag+0); af1 = *(const float4*)(ag+4);
      af2 = *(const float4*)(ag+8); af3 = *(const float4*)(ag+12);
      const uint16_t* bg = bgp + (kt+1)*32;
      bu0 = *(const uint4*)(bg); bu1 = *(const uint4*)(bg+8);
    }
    short8 a[4], b[4];
#pragma unroll
    for (int t = 0; t < 4; t++) a[t] = *(short8*)&As[(wm*64 + t*16 + lm)*32 + lq*8];
#pragma unroll
    for (int t = 0; t < 4; t++) b[t] = *(short8*)&Bs[(wn*64 + t*16 + lm)*32 + lq*8];
#pragma unroll
    for (int tm = 0; tm < 4; tm++)
#pragma unroll
      for (int tn = 0; tn < 4; tn++)
        acc[tm][tn] = __builtin_amdgcn_mfma_f32_16x16x32_bf16(a[tm], b[tn], acc[tm][tn], 0, 0, 0);
    __syncthreads();
  }
#pragma unroll
  for (int tn = 0; tn < 4; tn++) {
    int n = nb*128 + wn*64 + tn*16 + lm;
    float bias = bqkv[n];
    int which = n >> 9, c = n & 511;
    uint16_t* dst = (which == 0) ? qb : (which == 1) ? kb : vb;
    int hh = c >> 6, dd = c & 63;
#pragma unroll
    for (int tm = 0; tm < 4; tm++) {
#pragma unroll
      for (int r = 0; r < 4; r++) {
        int m = mb*128 + wm*64 + tm*16 + lq*4 + r;
        int bw = m / 145, nl = m - bw*145;
        dst[((size_t)(bw*8 + hh)*145 + nl)*64 + dd] = f2bf(acc[tm][tn][r] + bias);
      }
    }
  }
}

// ---------------- attention: S=QK^T, softmax, P*V ----------------
__global__ __launch_bounds__(256, 2) void attn_kernel(
    const uint16_t* __restrict__ qb, const uint16_t* __restrict__ kb,
    const uint16_t* __restrict__ vb, const float* __restrict__ biastab,
    const float* __restrict__ mask, float* __restrict__ glog,
    uint16_t* __restrict__ attn_out) {
  __shared__ __align__(16) uint16_t P[144*160];   // 46080 B, probs bf16, cols>=145 zero
  __shared__ __align__(16) uint16_t vs[145*64];   // 18560 B
  int bid = blockIdx.x;
  int b_ = bid >> 3, h = bid & 7;
  int nw = b_ & 3;
  int tid = threadIdx.x, lane = tid & 63, w = tid >> 6;
  int lm = lane & 15, lq = lane >> 4;
  const size_t hbase = ((size_t)(b_*8 + h)) * (145*64);
  const uint16_t* qp = qb + hbase;
  const uint16_t* kp = kb + hbase;
  const uint16_t* vp = vb + hbase;

  // stage V -> LDS (plain layout [j][d])
  for (int c = tid; c < 1160; c += 256)
    *(uint4*)&vs[c*8] = *(const uint4*)(vp + (size_t)c*8);

  // ----- S phase: wave w owns m-tiles {w, w+4, w+8} -----
  int nmt = (w < 2) ? 3 : 2;
  f32x4 acc[3][10];
#pragma unroll
  for (int a = 0; a < 3; a++)
#pragma unroll
    for (int b = 0; b < 10; b++) acc[a][b] = (f32x4){0.f,0.f,0.f,0.f};

#pragma unroll
  for (int ks = 0; ks < 2; ks++) {
    short8 bfr[10];
#pragma unroll
    for (int nt = 0; nt < 10; nt++) {
      int j = nt*16 + lm; if (j > 144) j = 144;
      bfr[nt] = *(const short8*)(kp + (size_t)j*64 + ks*32 + lq*8);
    }
#pragma unroll
    for (int mtl = 0; mtl < 3; mtl++) {
      if (mtl < nmt) {
        int mt = w + mtl*4;
        int i = mt*16 + lm; if (i > 144) i = 144;
        short8 afr = *(const short8*)(qp + (size_t)i*64 + ks*32 + lq*8);
#pragma unroll
        for (int nt = 0; nt < 10; nt++)
          acc[mtl][nt] = __builtin_amdgcn_mfma_f32_16x16x32_bf16(afr, bfr[nt], acc[mtl][nt], 0, 0, 0);
      }
    }
  }

  // ----- softmax (in-register, D-layout: row = 16*mt + lq*4 + r, col = 16*nt + lm) -----
  const float scale = 0.125f;
#pragma unroll
  for (int mtl = 0; mtl < 3; mtl++) {
    if (mtl >= nmt) continue;
    int mt = w + mtl*4;
    if (mt == 9) {
      // row 144 raw logits (+mask, no bias) -> glog
      if (lq == 0) {
#pragma unroll
        for (int nt = 0; nt < 10; nt++) {
          int j = nt*16 + lm;
          if (j < 145)
            glog[(size_t)(b_*8 + h)*145 + j] =
                acc[mtl][nt][0]*scale + mask[(nw*145 + 144)*145 + j];
        }
      }
      continue;
    }
#pragma unroll
    for (int r = 0; r < 4; r++) {
      int i = mt*16 + lq*4 + r;
      float mx = -3.0e38f;
#pragma unroll
      for (int nt = 0; nt < 10; nt++) {
        int j = nt*16 + lm;
        float t = acc[mtl][nt][r]*scale;
        if (j < 145) t += mask[(nw*145 + i)*145 + j];
        if (j < 144) t += biastab[(h*144 + i)*144 + j];
        if (j >= 145) t = -3.0e38f;
        acc[mtl][nt][r] = t;
        mx = fmaxf(mx, t);
      }
#pragma unroll
      for (int off = 1; off < 16; off <<= 1) mx = fmaxf(mx, __shfl_xor(mx, off));
      float sum = 0.f;
#pragma unroll
      for (int nt = 0; nt < 10; nt++) {
        int j = nt*16 + lm;
        float p = (j < 145) ? __expf(acc[mtl][nt][r] - mx) : 0.f;
        acc[mtl][nt][r] = p; sum += p;
      }
#pragma unroll
      for (int off = 1; off < 16; off <<= 1) sum += __shfl_xor(sum, off);
      float rs = __builtin_amdgcn_rcpf(sum);
#pragma unroll
      for (int nt = 0; nt < 10; nt++)
        P[i*160 + nt*16 + lm] = f2bf(acc[mtl][nt][r] * rs);
    }
  }
  __syncthreads();

  // ----- PV phase: wave w owns n-tile w (d = 16w+lm), all 9 m-tiles -----
  f32x4 oacc[9];
#pragma unroll
  for (int a = 0; a < 9; a++) oacc[a] = (f32x4){0.f,0.f,0.f,0.f};
#pragma unroll
  for (int ks = 0; ks < 5; ks++) {
    short8 bfr;
#pragma unroll
    for (int jj = 0; jj < 8; jj++) {
      int j = ks*32 + lq*8 + jj; if (j > 144) j = 144;
      bfr[jj] = (short)vs[j*64 + w*16 + lm];
    }
#pragma unroll
    for (int mt = 0; mt < 9; mt++) {
      short8 afr = *(short8*)&P[(mt*16 + lm)*160 + ks*32 + lq*8];
      oacc[mt] = __builtin_amdgcn_mfma_f32_16x16x32_bf16(afr, bfr, oacc[mt], 0, 0, 0);
    }
  }
#pragma unroll
  for (int mt = 0; mt < 9; mt++) {
#pragma unroll
    for (int r = 0; r < 4; r++) {
      int i = mt*16 + lq*4 + r;
      attn_out[((size_t)b_*145 + i)*512 + h*64 + w*16 + lm] = f2bf(oacc[mt][r]);
    }
  }
}

// ---------------- gx: global-token redistribution ----------------
__global__ __launch_bounds__(64) void gx_kernel(
    const float* __restrict__ glog, const uint16_t* __restrict__ vb,
    uint16_t* __restrict__ attn_out) {
  int bid = blockIdx.x;           // b*8 + h
  int b = bid >> 3, h = bid & 7;
  int lane = threadIdx.x;
  __shared__ float lg[580];
  __shared__ float pl[576];
  for (int nwi = 0; nwi < 4; nwi++)
    for (int t = lane; t < 145; t += 64)
      lg[nwi*145 + t] = glog[(size_t)((b*4 + nwi)*8 + h)*145 + t];
  __syncthreads();
  float g2 = 0.25f*(lg[144] + lg[289] + lg[434] + lg[579]);
  float mx = g2;
  for (int t = lane; t < 576; t += 64) {
    int nwi = t / 144, j = t - nwi*144;
    mx = fmaxf(mx, lg[nwi*145 + j]);
  }
#pragma unroll
  for (int off = 1; off < 64; off <<= 1) mx = fmaxf(mx, __shfl_xor(mx, off));
  float sum = 0.f;
  for (int t = lane; t < 576; t += 64) {
    int nwi = t / 144, j = t - nwi*144;
    float p = __expf(lg[nwi*145 + j] - mx);
    pl[t] = p; sum += p;
  }
#pragma unroll
  for (int off = 1; off < 64; off <<= 1) sum += __shfl_xor(sum, off);
  float p2 = __expf(g2 - mx);
  float rs = __builtin_amdgcn_rcpf(sum + p2);
  __syncthreads();
  float acc = 0.f;
  int d = lane;
  for (int nwi = 0; nwi < 4; nwi++) {
    const uint16_t* vp = vb + (size_t)((b*4 + nwi)*8 + h)*(145*64);
#pragma unroll 4
    for (int j = 0; j < 144; j++)
      acc += pl[nwi*144 + j] * bf2f(vp[j*64 + d]);
    acc += p2 * bf2f(vp[144*64 + d]);
  }
  acc *= rs;
  uint16_t o = f2bf(acc);
  for (int nwi = 0; nwi < 4; nwi++)
    attn_out[((size_t)(b*4 + nwi)*145 + 144)*512 + h*64 + d] = o;
}

// ---------------- GEMM 2: output projection ----------------
__global__ __launch_bounds__(256) void gemm_out(
    const uint16_t* __restrict__ A, const uint16_t* __restrict__ wo,
    const float* __restrict__ bo, float* __restrict__ out) {
  __shared__ __align__(16) uint16_t As[128*32];
  __shared__ __align__(16) uint16_t Bs[128*32];
  int bid = blockIdx.x;
  int mb = bid >> 2, nb = bid & 3;
  int tid = threadIdx.x;
  int lane = tid & 63, w = tid >> 6;
  int wm = w >> 1, wn = w & 1;
  int lm = lane & 15, lq = lane >> 4;
  int sr = tid >> 1, sh = tid & 1;

  const uint16_t* agp = A + (size_t)(mb*128 + sr)*512 + sh*16;
  const uint16_t* bgp = wo + (size_t)(nb*128 + sr)*512 + sh*16;

  f32x4 acc[4][4];
#pragma unroll
  for (int a = 0; a < 4; a++)
#pragma unroll
    for (int b = 0; b < 4; b++) acc[a][b] = (f32x4){0.f,0.f,0.f,0.f};

  uint4 au0 = *(const uint4*)(agp), au1 = *(const uint4*)(agp+8);
  uint4 bu0 = *(const uint4*)(bgp), bu1 = *(const uint4*)(bgp+8);

  for (int kt = 0; kt < 16; kt++) {
    *(uint4*)&As[sr*32 + sh*16]     = au0;
    *(uint4*)&As[sr*32 + sh*16 + 8] = au1;
    *(uint4*)&Bs[sr*32 + sh*16]     = bu0;
    *(uint4*)&Bs[sr*32 + sh*16 + 8] = bu1;
    __syncthreads();
    if (kt < 15) {
      const uint16_t* ag = agp + (kt+1)*32;
      au0 = *(const uint4*)(ag); au1 = *(const uint4*)(ag+8);
      const uint16_t* bg = bgp + (kt+1)*32;
      bu0 = *(const uint4*)(bg); bu1 = *(const uint4*)(bg+8);
    }
    short8 a[4], b[4];
#pragma unroll
    for (int t = 0; t < 4; t++) a[t] = *(short8*)&As[(wm*64 + t*16 + lm)*32 + lq*8];
#pragma unroll
    for (int t = 0; t < 4; t++) b[t] = *(short8*)&Bs[(wn*64 + t*16 + lm)*32 + lq*8];
#pragma unroll
    for (int tm = 0; tm < 4; tm++)
#pragma unroll
      for (int tn = 0; tn < 4; tn++)
        acc[tm][tn] = __builtin_amdgcn_mfma_f32_16x16x32_bf16(a[tm], b[tn], acc[tm][tn], 0, 0, 0);
    __syncthreads();
  }
#pragma unroll
  for (int tn = 0; tn < 4; tn++) {
    int n = nb*128 + wn*64 + tn*16 + lm;
    float bias = bo[n];
#pragma unroll
    for (int tm = 0; tm < 4; tm++) {
#pragma unroll
      for (int r = 0; r < 4; r++) {
        int m = mb*128 + wm*64 + tm*16 + lq*4 + r;
        out[(size_t)m*512 + n] = acc[tm][tn][r] + bias;
      }
    }
  }
}

// ---------------- launch ----------------
extern "C" void kernel_launch(void* const* d_in, const int* in_sizes, int n_in,
                              void* d_out, int out_size, void* d_ws, size_t ws_size,
                              hipStream_t stream) {
  const float* x    = (const float*)d_in[0];
  const float* mask = (const float*)d_in[1];
  const float* rpb  = (const float*)d_in[2];
  const float* Wq   = (const float*)d_in[3];
  const float* bq   = (const float*)d_in[4];
  const float* Wk   = (const float*)d_in[5];
  const float* bk   = (const float*)d_in[6];
  const float* Wv   = (const float*)d_in[7];
  const float* bv   = (const float*)d_in[8];
  const float* Wo   = (const float*)d_in[9];
  const float* bo   = (const float*)d_in[10];

  uint8_t* ws = (uint8_t*)d_ws;
  size_t off = 0;
  auto alloc = [&](size_t bytes) -> void* {
    void* p = ws + off; off += (bytes + 255) & ~(size_t)255; return p;
  };
  uint16_t* wqkv   = (uint16_t*)alloc((size_t)1536*512*2);
  uint16_t* wo     = (uint16_t*)alloc((size_t)512*512*2);
  float*    bqkv   = (float*)alloc(1536*4);
  float*    biastab= (float*)alloc((size_t)8*144*144*4);
  float*    glog   = (float*)alloc((size_t)512*8*145*4);
  uint16_t* qb     = (uint16_t*)alloc((size_t)MROWS*512*2);
  uint16_t* kb     = (uint16_t*)alloc((size_t)MROWS*512*2);
  uint16_t* vb     = (uint16_t*)alloc((size_t)MROWS*512*2);
  uint16_t* attn   = (uint16_t*)alloc((size_t)MROWS*512*2);

  prep_kernel<<<4750, 256, 0, stream>>>(rpb, Wq, bq, Wk, bk, Wv, bv, Wo,
                                        wqkv, wo, bqkv, biastab);
  gemm_qkv<<<580*12, 256, 0, stream>>>(x, wqkv, bqkv, qb, kb, vb);
  attn_kernel<<<4096, 256, 0, stream>>>(qb, kb, vb, biastab, mask, glog, attn);
  gx_kernel<<<1024, 64, 0, stream>>>(glog, vb, attn);
  gemm_out<<<580*4, 256, 0, stream>>>(attn, wo, bo, (float*)d_out);
}

// Round 2
// 726.068 us; speedup vs baseline: 1.1881x; 1.1881x over previous
//
#include <hip/hip_runtime.h>
#include <hip/hip_bf16.h>
#include <stdint.h>

#define NTOK 145
#define MTOK 144
#define CDIM 512
#define NHEAD 8
#define HD 64
#define NWIN 4
#define BWIN 512
#define MROWS (BWIN*NTOK)   // 74240 = 580*128

typedef short short8 __attribute__((ext_vector_type(8)));
typedef float f32x4 __attribute__((ext_vector_type(4)));

__device__ __forceinline__ uint16_t f2bf(float f) {
  union { float f; uint32_t u; } x; x.f = f;
  uint32_t r = x.u + 0x7FFFu + ((x.u >> 16) & 1u);
  return (uint16_t)(r >> 16);
}
__device__ __forceinline__ float bf2f(uint16_t u) {
  union { uint32_t u; float f; } x; x.u = ((uint32_t)u) << 16; return x.f;
}
__device__ __forceinline__ uint32_t pack2(float a, float b) {
  return (uint32_t)f2bf(a) | ((uint32_t)f2bf(b) << 16);
}

// async global->LDS, 16B per lane, LDS dest = wave-uniform base + lane*16
#define GLL(gp, lp) __builtin_amdgcn_global_load_lds( \
    (const __attribute__((address_space(1))) uint32_t*)(gp), \
    (__attribute__((address_space(3))) uint32_t*)(lp), 16, 0, 0)

// ---------------- cast x -> bf16 ----------------
__global__ __launch_bounds__(256) void cast_x(const float* __restrict__ x,
                                              uint16_t* __restrict__ xb) {
  size_t id = ((size_t)blockIdx.x*256 + threadIdx.x)*8;
  float4 a = *(const float4*)(x+id), c = *(const float4*)(x+id+4);
  uint4 o = make_uint4(pack2(a.x,a.y), pack2(a.z,a.w), pack2(c.x,c.y), pack2(c.z,c.w));
  *(uint4*)(xb+id) = o;
}

// ---------------- prep: weight casts + bias table ----------------
__global__ void prep_kernel(const float* __restrict__ rpb,
                            const float* __restrict__ Wq, const float* __restrict__ bq,
                            const float* __restrict__ Wk, const float* __restrict__ bk,
                            const float* __restrict__ Wv, const float* __restrict__ bv,
                            const float* __restrict__ Wo,
                            uint16_t* __restrict__ wqkv, uint16_t* __restrict__ wo,
                            float* __restrict__ bqkv, float* __restrict__ biastab) {
  int id = blockIdx.x * 256 + threadIdx.x;
  const int A = 1536*512, B = 512*512, C2 = 1536, D = 8*144*144;
  if (id < A) {
    int n = id >> 9, k = id & 511;
    const float* W = (n < 512) ? Wq : (n < 1024) ? Wk : Wv;
    wqkv[id] = f2bf(W[(size_t)(n & 511)*512 + k]);
  } else if ((id -= A) < B) {
    wo[id] = f2bf(Wo[id]);
  } else if ((id -= B) < C2) {
    bqkv[id] = (id < 512) ? bq[id] : (id < 1024) ? bk[id-512] : bv[id-1024];
  } else if ((id -= C2) < D) {
    int h = id / (144*144); int rr = id % (144*144);
    int i = rr / 144, j = rr % 144;
    int rel = (i/12 - j/12 + 11) * 23 + (i%12 - j%12 + 11);
    biastab[id] = rpb[rel*8 + h];
  }
}

// ---------------- GEMM 1: qkv projection (m97-style, bf16 A) ----------------
__global__ __launch_bounds__(256) void gemm_qkv(
    const uint16_t* __restrict__ xb, const uint16_t* __restrict__ wqkv,
    const float* __restrict__ bqkv,
    uint16_t* __restrict__ qb, uint16_t* __restrict__ kb, uint16_t* __restrict__ vb) {
  __shared__ __align__(16) uint16_t As[128*32];
  __shared__ __align__(16) uint16_t Bs[128*32];
  int bid = blockIdx.x;
  int mb, nb;
  // XCD swizzle: all 12 nb-blocks of one mb share bid%8 (same XCD), within 96-bid window
  if (bid < 6912) { int g = bid / 96, r = bid % 96; mb = g*8 + (r & 7); nb = r >> 3; }
  else           { int r = bid - 6912;              mb = 576 + (r & 3); nb = r >> 2; }
  int tid = threadIdx.x;
  int lane = tid & 63, w = tid >> 6;
  int wm = w >> 1, wn = w & 1;
  int lm = lane & 15, lq = lane >> 4;

  int srow = lane >> 2, scol = (lane & 3) * 8;
  const uint16_t* agp = xb   + (size_t)(mb*128 + w*32 + srow)*512 + scol;
  const uint16_t* bgp = wqkv + (size_t)(nb*128 + w*32 + srow)*512 + scol;
  uint16_t* Asw = &As[w*32*32];
  uint16_t* Bsw = &Bs[w*32*32];

  f32x4 acc[4][4];
#pragma unroll
  for (int a = 0; a < 4; a++)
#pragma unroll
    for (int b = 0; b < 4; b++) acc[a][b] = (f32x4){0.f,0.f,0.f,0.f};

  for (int kt = 0; kt < 16; kt++) {
    GLL(agp + kt*32,          Asw);
    GLL(agp + kt*32 + 16*512, Asw + 16*32);
    GLL(bgp + kt*32,          Bsw);
    GLL(bgp + kt*32 + 16*512, Bsw + 16*32);
    __syncthreads();
    short8 a[4], b[4];
#pragma unroll
    for (int t = 0; t < 4; t++) a[t] = *(short8*)&As[(wm*64 + t*16 + lm)*32 + lq*8];
#pragma unroll
    for (int t = 0; t < 4; t++) b[t] = *(short8*)&Bs[(wn*64 + t*16 + lm)*32 + lq*8];
#pragma unroll
    for (int tm = 0; tm < 4; tm++)
#pragma unroll
      for (int tn = 0; tn < 4; tn++)
        acc[tm][tn] = __builtin_amdgcn_mfma_f32_16x16x32_bf16(a[tm], b[tn], acc[tm][tn], 0, 0, 0);
    __syncthreads();
  }
#pragma unroll
  for (int tn = 0; tn < 4; tn++) {
    int n = nb*128 + wn*64 + tn*16 + lm;
    float bias = bqkv[n];
    int which = n >> 9, c = n & 511;
    uint16_t* dst = (which == 0) ? qb : (which == 1) ? kb : vb;
    int hh = c >> 6, dd = c & 63;
#pragma unroll
    for (int tm = 0; tm < 4; tm++) {
#pragma unroll
      for (int r = 0; r < 4; r++) {
        int m = mb*128 + wm*64 + tm*16 + lq*4 + r;
        int bw = m / 145, nl = m - bw*145;
        dst[((size_t)(bw*8 + hh)*145 + nl)*64 + dd] = f2bf(acc[tm][tn][r] + bias);
      }
    }
  }
}

// ---------------- attention: S=QK^T, softmax, P*V ----------------
__global__ __launch_bounds__(256, 2) void attn_kernel(
    const uint16_t* __restrict__ qb, const uint16_t* __restrict__ kb,
    const uint16_t* __restrict__ vb, const float* __restrict__ biastab,
    const float* __restrict__ mask, float* __restrict__ glog,
    uint16_t* __restrict__ attn_out) {
  __shared__ __align__(16) uint16_t P[144*160];   // probs bf16, cols>=145 zero
  __shared__ __align__(16) uint16_t vs[145*64];
  int bid = blockIdx.x;
  int b_ = bid >> 3, h = bid & 7;
  int nw = b_ & 3;
  int tid = threadIdx.x, lane = tid & 63, w = tid >> 6;
  int lm = lane & 15, lq = lane >> 4;
  const size_t hbase = ((size_t)(b_*8 + h)) * (145*64);
  const uint16_t* qp = qb + hbase;
  const uint16_t* kp = kb + hbase;
  const uint16_t* vp = vb + hbase;

  for (int c = tid; c < 1160; c += 256)
    *(uint4*)&vs[c*8] = *(const uint4*)(vp + (size_t)c*8);

  int nmt = (w < 2) ? 3 : 2;
  f32x4 acc[3][10];
#pragma unroll
  for (int a = 0; a < 3; a++)
#pragma unroll
    for (int b = 0; b < 10; b++) acc[a][b] = (f32x4){0.f,0.f,0.f,0.f};

#pragma unroll
  for (int ks = 0; ks < 2; ks++) {
    short8 bfr[10];
#pragma unroll
    for (int nt = 0; nt < 10; nt++) {
      int j = nt*16 + lm; if (j > 144) j = 144;
      bfr[nt] = *(const short8*)(kp + (size_t)j*64 + ks*32 + lq*8);
    }
#pragma unroll
    for (int mtl = 0; mtl < 3; mtl++) {
      if (mtl < nmt) {
        int mt = w + mtl*4;
        int i = mt*16 + lm; if (i > 144) i = 144;
        short8 afr = *(const short8*)(qp + (size_t)i*64 + ks*32 + lq*8);
#pragma unroll
        for (int nt = 0; nt < 10; nt++)
          acc[mtl][nt] = __builtin_amdgcn_mfma_f32_16x16x32_bf16(afr, bfr[nt], acc[mtl][nt], 0, 0, 0);
      }
    }
  }

  const float scale = 0.125f;
#pragma unroll
  for (int mtl = 0; mtl < 3; mtl++) {
    if (mtl >= nmt) continue;
    int mt = w + mtl*4;
    if (mt == 9) {
      if (lq == 0) {
#pragma unroll
        for (int nt = 0; nt < 10; nt++) {
          int j = nt*16 + lm;
          if (j < 145)
            glog[(size_t)(b_*8 + h)*145 + j] =
                acc[mtl][nt][0]*scale + mask[(nw*145 + 144)*145 + j];
        }
      }
      continue;
    }
#pragma unroll
    for (int r = 0; r < 4; r++) {
      int i = mt*16 + lq*4 + r;
      float mx = -3.0e38f;
#pragma unroll
      for (int nt = 0; nt < 10; nt++) {
        int j = nt*16 + lm;
        float t = acc[mtl][nt][r]*scale;
        if (j < 145) t += mask[(nw*145 + i)*145 + j];
        if (j < 144) t += biastab[(h*144 + i)*144 + j];
        if (j >= 145) t = -3.0e38f;
        acc[mtl][nt][r] = t;
        mx = fmaxf(mx, t);
      }
#pragma unroll
      for (int off = 1; off < 16; off <<= 1) mx = fmaxf(mx, __shfl_xor(mx, off));
      float sum = 0.f;
#pragma unroll
      for (int nt = 0; nt < 10; nt++) {
        int j = nt*16 + lm;
        float p = (j < 145) ? __expf(acc[mtl][nt][r] - mx) : 0.f;
        acc[mtl][nt][r] = p; sum += p;
      }
#pragma unroll
      for (int off = 1; off < 16; off <<= 1) sum += __shfl_xor(sum, off);
      float rs = __builtin_amdgcn_rcpf(sum);
#pragma unroll
      for (int nt = 0; nt < 10; nt++)
        P[i*160 + nt*16 + lm] = f2bf(acc[mtl][nt][r] * rs);
    }
  }
  __syncthreads();

  f32x4 oacc[9];
#pragma unroll
  for (int a = 0; a < 9; a++) oacc[a] = (f32x4){0.f,0.f,0.f,0.f};
#pragma unroll
  for (int ks = 0; ks < 5; ks++) {
    short8 bfr;
#pragma unroll
    for (int jj = 0; jj < 8; jj++) {
      int j = ks*32 + lq*8 + jj; if (j > 144) j = 144;
      bfr[jj] = (short)vs[j*64 + w*16 + lm];
    }
#pragma unroll
    for (int mt = 0; mt < 9; mt++) {
      short8 afr = *(short8*)&P[(mt*16 + lm)*160 + ks*32 + lq*8];
      oacc[mt] = __builtin_amdgcn_mfma_f32_16x16x32_bf16(afr, bfr, oacc[mt], 0, 0, 0);
    }
  }
#pragma unroll
  for (int mt = 0; mt < 9; mt++) {
#pragma unroll
    for (int r = 0; r < 4; r++) {
      int i = mt*16 + lq*4 + r;
      attn_out[((size_t)b_*145 + i)*512 + h*64 + w*16 + lm] = f2bf(oacc[mt][r]);
    }
  }
}

// ---------------- gx: global-token redistribution (4 waves) ----------------
__global__ __launch_bounds__(256) void gx_kernel(
    const float* __restrict__ glog, const uint16_t* __restrict__ vb,
    uint16_t* __restrict__ attn_out) {
  int bid = blockIdx.x;           // b*8 + h
  int b = bid >> 3, h = bid & 7;
  int tid = threadIdx.x, lane = tid & 63, w = tid >> 6;
  __shared__ float lg[580];
  __shared__ float pl[576];
  __shared__ float sred[8];
  __shared__ float sacc[256];
  for (int t = tid; t < 580; t += 256) {
    int nwi = t / 145, j = t - nwi*145;
    lg[t] = glog[(size_t)((b*4 + nwi)*8 + h)*145 + j];
  }
  __syncthreads();
  float g2 = 0.25f*(lg[144] + lg[289] + lg[434] + lg[579]);
  float mx = g2;
  for (int t = tid; t < 576; t += 256) {
    int nwi = t / 144, j = t - nwi*144;
    mx = fmaxf(mx, lg[nwi*145 + j]);
  }
#pragma unroll
  for (int off = 1; off < 64; off <<= 1) mx = fmaxf(mx, __shfl_xor(mx, off));
  if (lane == 0) sred[w] = mx;
  __syncthreads();
  mx = fmaxf(fmaxf(sred[0], sred[1]), fmaxf(sred[2], sred[3]));
  float sum = 0.f;
  for (int t = tid; t < 576; t += 256) {
    int nwi = t / 144, j = t - nwi*144;
    float p = __expf(lg[nwi*145 + j] - mx);
    pl[t] = p; sum += p;
  }
#pragma unroll
  for (int off = 1; off < 64; off <<= 1) sum += __shfl_xor(sum, off);
  if (lane == 0) sred[4 + w] = sum;
  __syncthreads();
  sum = (sred[4] + sred[5]) + (sred[6] + sred[7]);
  float p2 = __expf(g2 - mx);
  float rs = __builtin_amdgcn_rcpf(sum + p2);
  // wave w handles window nwi=w
  const uint16_t* vp = vb + (size_t)((b*4 + w)*8 + h)*(145*64);
  float acc = 0.f;
  int d = lane;
#pragma unroll 4
  for (int j = 0; j < 144; j++)
    acc += pl[w*144 + j] * bf2f(vp[j*64 + d]);
  acc += p2 * bf2f(vp[144*64 + d]);
  sacc[tid] = acc;
  __syncthreads();
  if (w == 0) {
    float tot = (sacc[lane] + sacc[64 + lane]) + (sacc[128 + lane] + sacc[192 + lane]);
    uint16_t o = f2bf(tot * rs);
    for (int nwi = 0; nwi < 4; nwi++)
      attn_out[((size_t)(b*4 + nwi)*145 + 144)*512 + h*64 + d] = o;
  }
}

// ---------------- GEMM 2: output projection (m97-style) ----------------
__global__ __launch_bounds__(256) void gemm_out(
    const uint16_t* __restrict__ A, const uint16_t* __restrict__ wo,
    const float* __restrict__ bo, float* __restrict__ out) {
  __shared__ __align__(16) uint16_t As[128*32];
  __shared__ __align__(16) uint16_t Bs[128*32];
  int bid = blockIdx.x;
  int mb, nb;
  if (bid < 2304) { int g = bid / 32, r = bid % 32; mb = g*8 + (r & 7); nb = r >> 3; }
  else            { int r = bid - 2304;             mb = 576 + (r & 3); nb = r >> 2; }
  int tid = threadIdx.x;
  int lane = tid & 63, w = tid >> 6;
  int wm = w >> 1, wn = w & 1;
  int lm = lane & 15, lq = lane >> 4;

  int srow = lane >> 2, scol = (lane & 3) * 8;
  const uint16_t* agp = A  + (size_t)(mb*128 + w*32 + srow)*512 + scol;
  const uint16_t* bgp = wo + (size_t)(nb*128 + w*32 + srow)*512 + scol;
  uint16_t* Asw = &As[w*32*32];
  uint16_t* Bsw = &Bs[w*32*32];

  f32x4 acc[4][4];
#pragma unroll
  for (int a = 0; a < 4; a++)
#pragma unroll
    for (int b = 0; b < 4; b++) acc[a][b] = (f32x4){0.f,0.f,0.f,0.f};

  for (int kt = 0; kt < 16; kt++) {
    GLL(agp + kt*32,          Asw);
    GLL(agp + kt*32 + 16*512, Asw + 16*32);
    GLL(bgp + kt*32,          Bsw);
    GLL(bgp + kt*32 + 16*512, Bsw + 16*32);
    __syncthreads();
    short8 a[4], b[4];
#pragma unroll
    for (int t = 0; t < 4; t++) a[t] = *(short8*)&As[(wm*64 + t*16 + lm)*32 + lq*8];
#pragma unroll
    for (int t = 0; t < 4; t++) b[t] = *(short8*)&Bs[(wn*64 + t*16 + lm)*32 + lq*8];
#pragma unroll
    for (int tm = 0; tm < 4; tm++)
#pragma unroll
      for (int tn = 0; tn < 4; tn++)
        acc[tm][tn] = __builtin_amdgcn_mfma_f32_16x16x32_bf16(a[tm], b[tn], acc[tm][tn], 0, 0, 0);
    __syncthreads();
  }
#pragma unroll
  for (int tn = 0; tn < 4; tn++) {
    int n = nb*128 + wn*64 + tn*16 + lm;
    float bias = bo[n];
#pragma unroll
    for (int tm = 0; tm < 4; tm++) {
#pragma unroll
      for (int r = 0; r < 4; r++) {
        int m = mb*128 + wm*64 + tm*16 + lq*4 + r;
        out[(size_t)m*512 + n] = acc[tm][tn][r] + bias;
      }
    }
  }
}

// ---------------- launch ----------------
extern "C" void kernel_launch(void* const* d_in, const int* in_sizes, int n_in,
                              void* d_out, int out_size, void* d_ws, size_t ws_size,
                              hipStream_t stream) {
  const float* x    = (const float*)d_in[0];
  const float* mask = (const float*)d_in[1];
  const float* rpb  = (const float*)d_in[2];
  const float* Wq   = (const float*)d_in[3];
  const float* bq   = (const float*)d_in[4];
  const float* Wk   = (const float*)d_in[5];
  const float* bk   = (const float*)d_in[6];
  const float* Wv   = (const float*)d_in[7];
  const float* bv   = (const float*)d_in[8];
  const float* Wo   = (const float*)d_in[9];
  const float* bo   = (const float*)d_in[10];

  uint8_t* ws = (uint8_t*)d_ws;
  size_t off = 0;
  auto alloc = [&](size_t bytes) -> void* {
    void* p = ws + off; off += (bytes + 255) & ~(size_t)255; return p;
  };
  uint16_t* wqkv   = (uint16_t*)alloc((size_t)1536*512*2);
  uint16_t* wo     = (uint16_t*)alloc((size_t)512*512*2);
  float*    bqkv   = (float*)alloc(1536*4);
  float*    biastab= (float*)alloc((size_t)8*144*144*4);
  float*    glog   = (float*)alloc((size_t)512*8*145*4);
  uint16_t* xb     = (uint16_t*)alloc((size_t)MROWS*512*2);
  uint16_t* qb     = (uint16_t*)alloc((size_t)MROWS*512*2);
  uint16_t* kb     = (uint16_t*)alloc((size_t)MROWS*512*2);
  uint16_t* vb     = (uint16_t*)alloc((size_t)MROWS*512*2);
  uint16_t* attn   = (uint16_t*)alloc((size_t)MROWS*512*2);

  cast_x<<<18560, 256, 0, stream>>>(x, xb);
  prep_kernel<<<4750, 256, 0, stream>>>(rpb, Wq, bq, Wk, bk, Wv, bv, Wo,
                                        wqkv, wo, bqkv, biastab);
  gemm_qkv<<<580*12, 256, 0, stream>>>(xb, wqkv, bqkv, qb, kb, vb);
  attn_kernel<<<4096, 256, 0, stream>>>(qb, kb, vb, biastab, mask, glog, attn);
  gx_kernel<<<1024, 256, 0, stream>>>(glog, vb, attn);
  gemm_out<<<580*4, 256, 0, stream>>>(attn, wo, bo, (float*)d_out);
}